// Round 4
// baseline (1239.134 us; speedup 1.0000x reference)
//
#include <hip/hip_runtime.h>
#include <hip/hip_bf16.h>
#include <stdint.h>

typedef unsigned short u16;
typedef __attribute__((ext_vector_type(8))) short bf16x8;
typedef __attribute__((ext_vector_type(4))) float f32x4;

constexpr int T_ = 8192;
constexpr int D_ = 1024;
constexpr int H_ = 4096;
constexpr int E_ = 8;
// 256-row m-tiles; expert offsets 256-aligned. Worst case: routed 16384+8*255
// -> 72 tiles, shared 8192 -> 32 tiles. Total 104 tiles = 26624 rows.
constexpr int NT_M  = 104;
constexpr int MAXR  = NT_M * 256;

__device__ __forceinline__ unsigned int f2bf_bits(float f) {
  unsigned int u = __float_as_uint(f);
  return (u + 0x7fffu + ((u >> 16) & 1u)) >> 16;
}
__device__ __forceinline__ float bf2f(u16 b) {
  return __uint_as_float(((unsigned int)b) << 16);
}

__device__ __forceinline__ void load_lds16(const void* g, void* s) {
  __builtin_amdgcn_global_load_lds(
      (const __attribute__((address_space(1))) unsigned int*)g,
      (__attribute__((address_space(3))) unsigned int*)s, 16, 0, 0);
}

// ---------------- router: fp32 logits, top-2, renormalized weights ----------
__global__ __launch_bounds__(256) void router_kernel(
    const float* __restrict__ x, const float* __restrict__ rw,
    int* __restrict__ counts, int* __restrict__ tok2, float* __restrict__ wgt2) {
  __shared__ float rw_s[E_ * D_];
  __shared__ int c_s[E_];
  const int tid = threadIdx.x;
  if (tid < E_) c_s[tid] = 0;
  for (int f = tid; f < 2048; f += 256) {
    int d = f >> 1, p = f & 1;
    float4 v = *(const float4*)(rw + d * 8 + p * 4);
    rw_s[(p * 4 + 0) * D_ + d] = v.x;
    rw_s[(p * 4 + 1) * D_ + d] = v.y;
    rw_s[(p * 4 + 2) * D_ + d] = v.z;
    rw_s[(p * 4 + 3) * D_ + d] = v.w;
  }
  __syncthreads();
  const int wid = tid >> 6, lane = tid & 63;
  for (int ti = 0; ti < 16; ++ti) {
    const int t = blockIdx.x * 64 + wid * 16 + ti;
    const float* xr = x + (long)t * D_;
    float acc[E_] = {0.f, 0.f, 0.f, 0.f, 0.f, 0.f, 0.f, 0.f};
    for (int j = 0; j < 16; ++j) {
      const int d = lane + 64 * j;
      const float xv = xr[d];
#pragma unroll
      for (int e = 0; e < E_; ++e) acc[e] += xv * rw_s[e * D_ + d];
    }
#pragma unroll
    for (int off = 32; off >= 1; off >>= 1) {
#pragma unroll
      for (int e = 0; e < E_; ++e) acc[e] += __shfl_xor(acc[e], off, 64);
    }
    if (lane == 0) {
      int i0 = 0; float l0 = acc[0];
#pragma unroll
      for (int e = 1; e < E_; ++e) if (acc[e] > l0) { l0 = acc[e]; i0 = e; }
      int i1 = -1; float l1 = -3.4e38f;
#pragma unroll
      for (int e = 0; e < E_; ++e) if (e != i0 && acc[e] > l1) { l1 = acc[e]; i1 = e; }
      const float r = __expf(l1 - l0);
      const float inv = 1.f / (1.f + r);
      tok2[2 * t] = i0; tok2[2 * t + 1] = i1;
      wgt2[2 * t] = inv; wgt2[2 * t + 1] = r * inv;
      atomicAdd(&c_s[i0], 1); atomicAdd(&c_s[i1], 1);
    }
  }
  __syncthreads();
  if (tid < E_) atomicAdd(&counts[tid], c_s[tid]);
}

// ---------------- scan: 256-aligned offsets, tile->expert table ------------
__global__ void scan_kernel(const int* __restrict__ counts, int* __restrict__ offs,
                            int* __restrict__ tile_expert, int* __restrict__ rowtok) {
  __shared__ int so[10];
  const int tid = threadIdx.x;
  if (tid == 0) {
    int o = 0;
    for (int e = 0; e < E_; ++e) { so[e] = o; o += ((counts[e] + 255) >> 8) << 8; }
    so[8] = o;          // shared-expert row base (256-aligned)
    o += T_;
    so[9] = o;          // actual total rows (<= MAXR)
    for (int i = 0; i < 10; ++i) offs[i] = so[i];
  }
  __syncthreads();
  for (int i = tid; i < NT_M; i += 256) {
    const int row = i << 8;
    int e;
    if (row < so[8]) {
      e = 7;
      for (int k = 0; k < 7; ++k) if (row < so[k + 1]) { e = k; break; }
    } else if (row < so[9]) {
      e = 8;
    } else {
      e = -1;          // dead tile: blocks early-exit
    }
    tile_expert[i] = e;
  }
  for (int r = tid; r < MAXR; r += 256) rowtok[r] = 0;
}

// ---------------- assign: scatter tokens into per-expert row ranges --------
__global__ __launch_bounds__(256) void assign_kernel(
    const int* __restrict__ tok2, const int* __restrict__ offs,
    int* __restrict__ cursors, int* __restrict__ rowtok, int* __restrict__ pos2) {
  __shared__ int lcnt[E_], lbase[E_];
  const int tid = threadIdx.x;
  if (tid < E_) lcnt[tid] = 0;
  __syncthreads();
  const int t = blockIdx.x * 256 + tid;
  const int e0 = tok2[2 * t], e1 = tok2[2 * t + 1];
  const int s0 = atomicAdd(&lcnt[e0], 1);
  const int s1 = atomicAdd(&lcnt[e1], 1);
  __syncthreads();
  if (tid < E_) lbase[tid] = offs[tid] + atomicAdd(&cursors[tid], lcnt[tid]);
  __syncthreads();
  const int p0 = lbase[e0] + s0, p1 = lbase[e1] + s1;
  rowtok[p0] = t; rowtok[p1] = t;
  pos2[2 * t] = p0; pos2[2 * t + 1] = p1;
  rowtok[offs[8] + t] = t;   // shared expert: identity
}

// ---------------- x fp32 -> bf16 -------------------------------------------
__global__ __launch_bounds__(256) void cvt_x_kernel(const float* __restrict__ x,
                                                    u16* __restrict__ xb) {
  const long i = ((long)blockIdx.x * 256 + threadIdx.x) * 4;
  const float4 v = *(const float4*)(x + i);
  ushort4 o;
  o.x = (u16)f2bf_bits(v.x); o.y = (u16)f2bf_bits(v.y);
  o.z = (u16)f2bf_bits(v.z); o.w = (u16)f2bf_bits(v.w);
  *(ushort4*)(xb + i) = o;
}

// ---------------- weight transpose + fp32->bf16 ([R,C] -> [C,R]) -----------
__global__ __launch_bounds__(256) void transpose_cvt_kernel(
    const float* __restrict__ src8, const float* __restrict__ srcShared,
    u16* __restrict__ dst, int R, int C) {
  __shared__ float tile[64][65];
  const long stride = (long)R * C;
  const float* src = (blockIdx.z < 8) ? src8 + (long)blockIdx.z * stride : srcShared;
  u16* d = dst + (long)blockIdx.z * stride;
  const int tid = threadIdx.x;
  const int r0 = blockIdx.y * 64, c0 = blockIdx.x * 64;
  const int lr = tid >> 4, lc4 = tid & 15;
#pragma unroll
  for (int p = 0; p < 4; ++p) {
    const float4 v = *(const float4*)(src + (long)(r0 + lr + 16 * p) * C + c0 + lc4 * 4);
    tile[lr + 16 * p][lc4 * 4 + 0] = v.x;
    tile[lr + 16 * p][lc4 * 4 + 1] = v.y;
    tile[lr + 16 * p][lc4 * 4 + 2] = v.z;
    tile[lr + 16 * p][lc4 * 4 + 3] = v.w;
  }
  __syncthreads();
#pragma unroll
  for (int p = 0; p < 4; ++p) {
    const int rr = lr + 16 * p;
    ushort4 o;
    o.x = (u16)f2bf_bits(tile[lc4 * 4 + 0][rr]);
    o.y = (u16)f2bf_bits(tile[lc4 * 4 + 1][rr]);
    o.z = (u16)f2bf_bits(tile[lc4 * 4 + 2][rr]);
    o.w = (u16)f2bf_bits(tile[lc4 * 4 + 3][rr]);
    *(ushort4*)(d + (long)(c0 + rr) * R + r0 + lc4 * 4) = o;
  }
}

// ---------------- grouped GEMM: 256x128 block tile, 128x64 wave tile --------
// G1: h[row,n] = silu( sum_k xb[rowtok[row],k] * w1t[e][n,k] )  (bf16 out)
// G2: eo[row,n] = sum_k h[row,k] * w2t[e][n,k]                  (bf16 out)
// LDS is staged in FRAGMENT ORDER: staging lane tid of call c fetches global
// (row = 64c + (tid>>6)*16 + (tid&15), kchunk = (tid>>4)&3) into LDS tid*16B.
// Then MFMA fragment i reads at As + wmh*4096 + i*512 + lane*8 -- the exact
// 64-lane x 16B contiguous pattern of the write: conflict-free by construction.
// Double-buffered, one barrier per k-step (prefetch issued after the barrier).
template <bool G1, int CHM>
__global__ __launch_bounds__(256, 2) void moe_gemm(
    const u16* __restrict__ A, const u16* __restrict__ Bt, u16* __restrict__ C,
    const int* __restrict__ rowtok, const int* __restrict__ tile_expert) {
  constexpr int K = G1 ? 1024 : 4096;
  constexpr int N = G1 ? 4096 : 1024;
  constexpr int NTn = N / 128;
  __shared__ u16 As[2 * 8192];   // 2 x (256 rows x 32 k) = 2 x 16 KB
  __shared__ u16 Bs[2 * 4096];   // 2 x (128 rows x 32 k) = 2 x  8 KB

  const int tid = threadIdx.x;
  int mt, nt;
  {
    const int bid = blockIdx.x;
    const int cb = CHM * NTn;
    const int chunk = bid / cb;
    const int mt0 = chunk * CHM;
    const int m = min(CHM, NT_M - mt0);
    const int rem = bid - chunk * cb;
    mt = mt0 + rem % m;
    nt = rem / m;
  }
  const int e = tile_expert[mt];
  if (e < 0) return;                 // dead tile (beyond actual row count)

  // staging source decomposition (fragment-ordered)
  const int ric   = ((tid >> 6) << 4) | (tid & 15);   // row within 64-row call
  const int sc    = ((tid >> 4) & 3) << 3;            // k offset {0,8,16,24}

  const u16* pa[4];
#pragma unroll
  for (int c = 0; c < 4; ++c) {
    const int grow = mt * 256 + c * 64 + ric;
    const long arow = G1 ? (long)rowtok[grow] : (long)grow;
    pa[c] = A + arow * K + sc;
  }
  const u16* pb[2];
#pragma unroll
  for (int c = 0; c < 2; ++c)
    pb[c] = Bt + (long)e * N * K + (long)(nt * 128 + c * 64 + ric) * K + sc;

  const int lane = tid & 63;
  const int wid = tid >> 6;
  const int wmh = wid >> 1;              // 0/1 -> rows 0-127 / 128-255
  const int wnh = wid & 1;               // 0/1 -> cols 0-63 / 64-127
  const int wm = wmh * 128, wn = wnh * 64;
  const int lr = lane & 15;
  const int quad = lane >> 4;
  const int lane8 = lane * 8;

  f32x4 acc[8][4] = {};

  // prologue: fill buffer 0 with k=0
#pragma unroll
  for (int c = 0; c < 4; ++c) load_lds16(pa[c], As + c * 2048 + tid * 8);
#pragma unroll
  for (int c = 0; c < 2; ++c) load_lds16(pb[c], Bs + c * 2048 + tid * 8);

#pragma unroll 1
  for (int k0 = 0; k0 < K; k0 += 64) {
    // ---- sub-iter 0: compute buf0, prefetch k0+32 -> buf1 ----
    __syncthreads();
    if (k0 + 32 < K) {
#pragma unroll
      for (int c = 0; c < 4; ++c)
        load_lds16(pa[c] + k0 + 32, As + 8192 + c * 2048 + tid * 8);
#pragma unroll
      for (int c = 0; c < 2; ++c)
        load_lds16(pb[c] + k0 + 32, Bs + 4096 + c * 2048 + tid * 8);
    }
    {
      bf16x8 af[8], bfv[4];
#pragma unroll
      for (int j = 0; j < 4; ++j)
        bfv[j] = *(const bf16x8*)(Bs + wnh * 2048 + j * 512 + lane8);
#pragma unroll
      for (int i = 0; i < 8; ++i)
        af[i] = *(const bf16x8*)(As + wmh * 4096 + i * 512 + lane8);
#pragma unroll
      for (int i = 0; i < 8; ++i)
#pragma unroll
        for (int j = 0; j < 4; ++j)
          acc[i][j] = __builtin_amdgcn_mfma_f32_16x16x32_bf16(af[i], bfv[j], acc[i][j], 0, 0, 0);
    }
    // ---- sub-iter 1: compute buf1, prefetch k0+64 -> buf0 ----
    __syncthreads();
    if (k0 + 64 < K) {
#pragma unroll
      for (int c = 0; c < 4; ++c)
        load_lds16(pa[c] + k0 + 64, As + c * 2048 + tid * 8);
#pragma unroll
      for (int c = 0; c < 2; ++c)
        load_lds16(pb[c] + k0 + 64, Bs + c * 2048 + tid * 8);
    }
    {
      bf16x8 af[8], bfv[4];
#pragma unroll
      for (int j = 0; j < 4; ++j)
        bfv[j] = *(const bf16x8*)(Bs + 4096 + wnh * 2048 + j * 512 + lane8);
#pragma unroll
      for (int i = 0; i < 8; ++i)
        af[i] = *(const bf16x8*)(As + 8192 + wmh * 4096 + i * 512 + lane8);
#pragma unroll
      for (int i = 0; i < 8; ++i)
#pragma unroll
        for (int j = 0; j < 4; ++j)
          acc[i][j] = __builtin_amdgcn_mfma_f32_16x16x32_bf16(af[i], bfv[j], acc[i][j], 0, 0, 0);
    }
  }

  // epilogue: bf16 output, pack adjacent-col pairs via shfl
  const int rbase = mt * 256 + wm + quad * 4;
#pragma unroll
  for (int i = 0; i < 8; ++i) {
#pragma unroll
    for (int j = 0; j < 4; ++j) {
#pragma unroll
      for (int r = 0; r < 4; ++r) {
        float v = acc[i][j][r];
        if constexpr (G1) v = v / (1.f + __expf(-v));   // silu
        unsigned int u = f2bf_bits(v);
        unsigned int other = (unsigned int)__shfl_xor((int)u, 1, 64);
        if (!(lane & 1)) {
          const unsigned int w = (u & 0xffffu) | (other << 16);
          const long row = rbase + i * 16 + r;
          const int col = nt * 128 + wn + j * 16 + lr;
          *(unsigned int*)(C + row * N + col) = w;
        }
      }
    }
  }
}

// ---------------- combine: out = w0*eo[p0] + w1*eo[p1] + eo[shared] ---------
__global__ __launch_bounds__(256) void combine_kernel(
    const u16* __restrict__ eo, const int* __restrict__ pos2,
    const float* __restrict__ wgt2, const int* __restrict__ offs,
    float* __restrict__ out) {
  const int t = blockIdx.x, tid = threadIdx.x;
  const int p0 = pos2[2 * t], p1 = pos2[2 * t + 1];
  const float w0 = wgt2[2 * t], w1 = wgt2[2 * t + 1];
  const int ps = offs[8] + t;
  const long c = (long)tid * 4;
  const ushort4 a = *(const ushort4*)(eo + (long)p0 * D_ + c);
  const ushort4 b = *(const ushort4*)(eo + (long)p1 * D_ + c);
  const ushort4 s = *(const ushort4*)(eo + (long)ps * D_ + c);
  float4 o;
  o.x = w0 * bf2f(a.x) + w1 * bf2f(b.x) + bf2f(s.x);
  o.y = w0 * bf2f(a.y) + w1 * bf2f(b.y) + bf2f(s.y);
  o.z = w0 * bf2f(a.z) + w1 * bf2f(b.z) + bf2f(s.z);
  o.w = w0 * bf2f(a.w) + w1 * bf2f(b.w) + bf2f(s.w);
  *(float4*)(out + (long)t * D_ + c) = o;
}

// ---------------------------------------------------------------------------
extern "C" void kernel_launch(void* const* d_in, const int* in_sizes, int n_in,
                              void* d_out, int out_size, void* d_ws, size_t ws_size,
                              hipStream_t stream) {
  const float* x   = (const float*)d_in[0];   // [T, D]
  const float* rw  = (const float*)d_in[1];   // [D, E]
  const float* w1  = (const float*)d_in[2];   // [E, D, H]
  const float* w2  = (const float*)d_in[3];   // [E, H, D]
  const float* sw1 = (const float*)d_in[4];   // [D, H]
  const float* sw2 = (const float*)d_in[5];   // [H, D]
  float* out = (float*)d_out;

  char* ws = (char*)d_ws;
  int*   counts      = (int*)(ws + 0);
  int*   cursors     = (int*)(ws + 64);
  int*   offs        = (int*)(ws + 128);
  int*   tile_expert = (int*)(ws + 512);
  int*   tok2        = (int*)(ws + 4096);
  float* wgt2        = (float*)(ws + 4096 + 65536);
  int*   pos2        = (int*)(ws + 4096 + 131072);
  int*   rowtok      = (int*)(ws + 4096 + 196608);

  size_t off = 1u << 20;
  u16* xb  = (u16*)(ws + off); off += (size_t)T_ * D_ * 2;            // 16.8 MB
  u16* w1t = (u16*)(ws + off); off += (size_t)9 * H_ * D_ * 2;        // 75.5 MB
  u16* w2t = (u16*)(ws + off); off += (size_t)9 * D_ * H_ * 2;        // 75.5 MB
  u16* h   = (u16*)(ws + off); off += (size_t)MAXR * H_ * 2;          // 218.1 MB
  u16* eo  = (u16*)(ws + off); off += (size_t)MAXR * D_ * 2;          // 54.5 MB

  hipMemsetAsync(ws, 0, 256, stream);   // counts + cursors
  router_kernel<<<128, 256, 0, stream>>>(x, rw, counts, tok2, wgt2);
  scan_kernel<<<1, 256, 0, stream>>>(counts, offs, tile_expert, rowtok);
  assign_kernel<<<32, 256, 0, stream>>>(tok2, offs, cursors, rowtok, pos2);
  cvt_x_kernel<<<T_ * D_ / 1024, 256, 0, stream>>>(x, xb);
  transpose_cvt_kernel<<<dim3(H_ / 64, D_ / 64, 9), 256, 0, stream>>>(w1, sw1, w1t, D_, H_);
  transpose_cvt_kernel<<<dim3(D_ / 64, H_ / 64, 9), 256, 0, stream>>>(w2, sw2, w2t, H_, D_);
  // chunk swizzle: CHM m-tiles x all n-tiles per chunk, m-fast within chunk
  moe_gemm<true, 16><<<NT_M * (H_ / 128), 256, 0, stream>>>(xb, w1t, h, rowtok, tile_expert);
  moe_gemm<false, 16><<<NT_M * (D_ / 128), 256, 0, stream>>>(h, w2t, eo, rowtok, tile_expert);
  combine_kernel<<<T_, 256, 0, stream>>>(eo, pos2, wgt2, offs, out);
}

// Round 5
// 1235.098 us; speedup vs baseline: 1.0033x; 1.0033x over previous
//
#include <hip/hip_runtime.h>
#include <hip/hip_bf16.h>
#include <stdint.h>

typedef unsigned short u16;
typedef __attribute__((ext_vector_type(8))) short bf16x8;
typedef __attribute__((ext_vector_type(4))) float f32x4;

constexpr int T_ = 8192;
constexpr int D_ = 1024;
constexpr int H_ = 4096;
constexpr int E_ = 8;
constexpr int MAXROWS = 25600;   // 200 tiles * 128 rows (worst-case padded)
constexpr int NTILES  = 200;

__device__ __forceinline__ unsigned int f2bf_bits(float f) {
  unsigned int u = __float_as_uint(f);
  return (u + 0x7fffu + ((u >> 16) & 1u)) >> 16;
}
__device__ __forceinline__ float bf2f(u16 b) {
  return __uint_as_float(((unsigned int)b) << 16);
}

__device__ __forceinline__ void load_lds16(const void* g, void* s) {
  __builtin_amdgcn_global_load_lds(
      (const __attribute__((address_space(1))) unsigned int*)g,
      (__attribute__((address_space(3))) unsigned int*)s, 16, 0, 0);
}

// ---------------- router: fp32 logits, top-2, renormalized weights ----------
__global__ __launch_bounds__(256) void router_kernel(
    const float* __restrict__ x, const float* __restrict__ rw,
    int* __restrict__ counts, int* __restrict__ tok2, float* __restrict__ wgt2) {
  __shared__ float rw_s[E_ * D_];
  __shared__ int c_s[E_];
  const int tid = threadIdx.x;
  if (tid < E_) c_s[tid] = 0;
  for (int f = tid; f < 2048; f += 256) {
    int d = f >> 1, p = f & 1;
    float4 v = *(const float4*)(rw + d * 8 + p * 4);
    rw_s[(p * 4 + 0) * D_ + d] = v.x;
    rw_s[(p * 4 + 1) * D_ + d] = v.y;
    rw_s[(p * 4 + 2) * D_ + d] = v.z;
    rw_s[(p * 4 + 3) * D_ + d] = v.w;
  }
  __syncthreads();
  const int wid = tid >> 6, lane = tid & 63;
  for (int ti = 0; ti < 16; ++ti) {
    const int t = blockIdx.x * 64 + wid * 16 + ti;
    const float* xr = x + (long)t * D_;
    float acc[E_] = {0.f, 0.f, 0.f, 0.f, 0.f, 0.f, 0.f, 0.f};
    for (int j = 0; j < 16; ++j) {
      const int d = lane + 64 * j;
      const float xv = xr[d];
#pragma unroll
      for (int e = 0; e < E_; ++e) acc[e] += xv * rw_s[e * D_ + d];
    }
#pragma unroll
    for (int off = 32; off >= 1; off >>= 1) {
#pragma unroll
      for (int e = 0; e < E_; ++e) acc[e] += __shfl_xor(acc[e], off, 64);
    }
    if (lane == 0) {
      int i0 = 0; float l0 = acc[0];
#pragma unroll
      for (int e = 1; e < E_; ++e) if (acc[e] > l0) { l0 = acc[e]; i0 = e; }
      int i1 = -1; float l1 = -3.4e38f;
#pragma unroll
      for (int e = 0; e < E_; ++e) if (e != i0 && acc[e] > l1) { l1 = acc[e]; i1 = e; }
      const float r = __expf(l1 - l0);
      const float inv = 1.f / (1.f + r);
      tok2[2 * t] = i0; tok2[2 * t + 1] = i1;
      wgt2[2 * t] = inv; wgt2[2 * t + 1] = r * inv;
      atomicAdd(&c_s[i0], 1); atomicAdd(&c_s[i1], 1);
    }
  }
  __syncthreads();
  if (tid < E_) atomicAdd(&counts[tid], c_s[tid]);
}

// ---------------- scan: 128-aligned offsets, tile->expert table ------------
__global__ void scan_kernel(const int* __restrict__ counts, int* __restrict__ offs,
                            int* __restrict__ tile_expert, int* __restrict__ rowtok) {
  __shared__ int so[10];
  const int tid = threadIdx.x;
  if (tid == 0) {
    int o = 0;
    for (int e = 0; e < E_; ++e) { so[e] = o; o += ((counts[e] + 127) >> 7) << 7; }
    so[8] = o;          // shared-expert row base
    o += T_;
    so[9] = o;          // actual total rows (<= MAXROWS)
    for (int i = 0; i < 10; ++i) offs[i] = so[i];
  }
  __syncthreads();
  for (int i = tid; i < NTILES; i += 256) {
    const int row = i << 7;
    int e;
    if (row < so[8]) {
      e = 7;
      for (int k = 0; k < 7; ++k) if (row < so[k + 1]) { e = k; break; }
    } else if (row < so[9]) {
      e = 8;
    } else {
      e = -1;          // dead tile: blocks early-exit
    }
    tile_expert[i] = e;
  }
  for (int r = tid; r < MAXROWS; r += 256) rowtok[r] = 0;
}

// ---------------- assign: scatter tokens into per-expert row ranges --------
__global__ __launch_bounds__(256) void assign_kernel(
    const int* __restrict__ tok2, const int* __restrict__ offs,
    int* __restrict__ cursors, int* __restrict__ rowtok, int* __restrict__ pos2) {
  __shared__ int lcnt[E_], lbase[E_];
  const int tid = threadIdx.x;
  if (tid < E_) lcnt[tid] = 0;
  __syncthreads();
  const int t = blockIdx.x * 256 + tid;
  const int e0 = tok2[2 * t], e1 = tok2[2 * t + 1];
  const int s0 = atomicAdd(&lcnt[e0], 1);
  const int s1 = atomicAdd(&lcnt[e1], 1);
  __syncthreads();
  if (tid < E_) lbase[tid] = offs[tid] + atomicAdd(&cursors[tid], lcnt[tid]);
  __syncthreads();
  const int p0 = lbase[e0] + s0, p1 = lbase[e1] + s1;
  rowtok[p0] = t; rowtok[p1] = t;
  pos2[2 * t] = p0; pos2[2 * t + 1] = p1;
  rowtok[offs[8] + t] = t;   // shared expert: identity
}

// ---------------- x fp32 -> bf16 -------------------------------------------
__global__ __launch_bounds__(256) void cvt_x_kernel(const float* __restrict__ x,
                                                    u16* __restrict__ xb) {
  const long i = ((long)blockIdx.x * 256 + threadIdx.x) * 4;
  const float4 v = *(const float4*)(x + i);
  ushort4 o;
  o.x = (u16)f2bf_bits(v.x); o.y = (u16)f2bf_bits(v.y);
  o.z = (u16)f2bf_bits(v.z); o.w = (u16)f2bf_bits(v.w);
  *(ushort4*)(xb + i) = o;
}

// ---------------- weight transpose + fp32->bf16 ([R,C] -> [C,R]) -----------
__global__ __launch_bounds__(256) void transpose_cvt_kernel(
    const float* __restrict__ src8, const float* __restrict__ srcShared,
    u16* __restrict__ dst, int R, int C) {
  __shared__ float tile[64][65];
  const long stride = (long)R * C;
  const float* src = (blockIdx.z < 8) ? src8 + (long)blockIdx.z * stride : srcShared;
  u16* d = dst + (long)blockIdx.z * stride;
  const int tid = threadIdx.x;
  const int r0 = blockIdx.y * 64, c0 = blockIdx.x * 64;
  const int lr = tid >> 4, lc4 = tid & 15;
#pragma unroll
  for (int p = 0; p < 4; ++p) {
    const float4 v = *(const float4*)(src + (long)(r0 + lr + 16 * p) * C + c0 + lc4 * 4);
    tile[lr + 16 * p][lc4 * 4 + 0] = v.x;
    tile[lr + 16 * p][lc4 * 4 + 1] = v.y;
    tile[lr + 16 * p][lc4 * 4 + 2] = v.z;
    tile[lr + 16 * p][lc4 * 4 + 3] = v.w;
  }
  __syncthreads();
#pragma unroll
  for (int p = 0; p < 4; ++p) {
    const int rr = lr + 16 * p;
    ushort4 o;
    o.x = (u16)f2bf_bits(tile[lc4 * 4 + 0][rr]);
    o.y = (u16)f2bf_bits(tile[lc4 * 4 + 1][rr]);
    o.z = (u16)f2bf_bits(tile[lc4 * 4 + 2][rr]);
    o.w = (u16)f2bf_bits(tile[lc4 * 4 + 3][rr]);
    *(ushort4*)(d + (long)(c0 + rr) * R + r0 + lc4 * 4) = o;
  }
}

// ---------------- grouped GEMM: 128x128 tile, dbuf, fragment-ordered LDS ----
// G1: h[row,n] = silu( sum_k xb[rowtok[row],k] * w1t[e][n,k] )  (bf16 out)
// G2: eo[row,n] = sum_k h[row,k] * w2t[e][n,k]                  (bf16 out)
// LDS staged in FRAGMENT ORDER (R4-proven conflict-free): staging lane tid of
// half c fetches global (row = 64c + ((tid>>6)<<4|(tid&15)), kchunk=(tid>>4)&3)
// into LDS tid*16B; MFMA fragment i then reads As + wmh*2048 + i*512 + lane*8
// == exact 64-lane x 16B write pattern. Double-buffered, 1 barrier/k-step.
// __launch_bounds__(256,4): cap unified regs at 128 (64 acc + ~60 arch)
// -> 4 blocks/CU (16 waves) for latency hiding of the HBM A-stream drain.
template <bool G1, int CHM>
__global__ __launch_bounds__(256, 4) void moe_gemm(
    const u16* __restrict__ A, const u16* __restrict__ Bt, u16* __restrict__ C,
    const int* __restrict__ rowtok, const int* __restrict__ tile_expert) {
  constexpr int K = G1 ? 1024 : 4096;
  constexpr int N = G1 ? 4096 : 1024;
  constexpr int NTn = N / 128;
  __shared__ u16 As[2 * 4096];   // 2 x (128 rows x 32 k) = 2 x 8 KB
  __shared__ u16 Bs[2 * 4096];

  const int tid = threadIdx.x;
  int mt, nt;
  {
    const int bid = blockIdx.x;
    const int cb = CHM * NTn;
    const int chunk = bid / cb;
    const int mt0 = chunk * CHM;
    const int m = min(CHM, NTILES - mt0);
    const int rem = bid - chunk * cb;
    mt = mt0 + rem % m;
    nt = rem / m;
  }
  const int e = tile_expert[mt];
  if (e < 0) return;               // dead tile

  // fragment-ordered staging source decomposition
  const int ric = ((tid >> 6) << 4) | (tid & 15);   // row within 64-row half
  const int sc  = ((tid >> 4) & 3) << 3;            // k offset {0,8,16,24}

  const u16* pa0;
  const u16* pa1;
  {
    const int g0 = mt * 128 + ric;
    const int g1 = g0 + 64;
    const long r0 = G1 ? (long)rowtok[g0] : (long)g0;
    const long r1 = G1 ? (long)rowtok[g1] : (long)g1;
    pa0 = A + r0 * K + sc;
    pa1 = A + r1 * K + sc;
  }
  const u16* pb0 = Bt + (long)e * N * K + (long)(nt * 128 + ric) * K + sc;
  const u16* pb1 = pb0 + (long)64 * K;

  const int lane = tid & 63;
  const int wid = tid >> 6;
  const int wmh = wid >> 1;        // A half
  const int wnh = wid & 1;         // B half
  const int lane8 = lane * 8;
  const int lr = lane & 15;
  const int quad = lane >> 4;

  f32x4 acc[4][4] = {};

  // prologue: fill buffer 0 with k=0
  load_lds16(pa0, As + tid * 8);
  load_lds16(pa1, As + 2048 + tid * 8);
  load_lds16(pb0, Bs + tid * 8);
  load_lds16(pb1, Bs + 2048 + tid * 8);

#pragma unroll 1
  for (int k0 = 0; k0 < K; k0 += 64) {
    // ---- sub-iter 0: compute buf0, prefetch k0+32 -> buf1 ----
    __syncthreads();
    if (k0 + 32 < K) {
      load_lds16(pa0 + k0 + 32, As + 4096 + tid * 8);
      load_lds16(pa1 + k0 + 32, As + 4096 + 2048 + tid * 8);
      load_lds16(pb0 + k0 + 32, Bs + 4096 + tid * 8);
      load_lds16(pb1 + k0 + 32, Bs + 4096 + 2048 + tid * 8);
    }
    {
      bf16x8 af[4], bfv[4];
#pragma unroll
      for (int j = 0; j < 4; ++j)
        bfv[j] = *(const bf16x8*)(Bs + wnh * 2048 + j * 512 + lane8);
#pragma unroll
      for (int i = 0; i < 4; ++i)
        af[i] = *(const bf16x8*)(As + wmh * 2048 + i * 512 + lane8);
#pragma unroll
      for (int i = 0; i < 4; ++i)
#pragma unroll
        for (int j = 0; j < 4; ++j)
          acc[i][j] = __builtin_amdgcn_mfma_f32_16x16x32_bf16(af[i], bfv[j], acc[i][j], 0, 0, 0);
    }
    // ---- sub-iter 1: compute buf1, prefetch k0+64 -> buf0 ----
    __syncthreads();
    if (k0 + 64 < K) {
      load_lds16(pa0 + k0 + 64, As + tid * 8);
      load_lds16(pa1 + k0 + 64, As + 2048 + tid * 8);
      load_lds16(pb0 + k0 + 64, Bs + tid * 8);
      load_lds16(pb1 + k0 + 64, Bs + 2048 + tid * 8);
    }
    {
      bf16x8 af[4], bfv[4];
#pragma unroll
      for (int j = 0; j < 4; ++j)
        bfv[j] = *(const bf16x8*)(Bs + 4096 + wnh * 2048 + j * 512 + lane8);
#pragma unroll
      for (int i = 0; i < 4; ++i)
        af[i] = *(const bf16x8*)(As + 4096 + wmh * 2048 + i * 512 + lane8);
#pragma unroll
      for (int i = 0; i < 4; ++i)
#pragma unroll
        for (int j = 0; j < 4; ++j)
          acc[i][j] = __builtin_amdgcn_mfma_f32_16x16x32_bf16(af[i], bfv[j], acc[i][j], 0, 0, 0);
    }
  }

  // epilogue: bf16 output, pack adjacent-col pairs via shfl
  const int rbase = mt * 128 + wmh * 64 + quad * 4;
  const int cbase = nt * 128 + wnh * 64 + lr;
#pragma unroll
  for (int i = 0; i < 4; ++i) {
#pragma unroll
    for (int j = 0; j < 4; ++j) {
#pragma unroll
      for (int r = 0; r < 4; ++r) {
        float v = acc[i][j][r];
        if constexpr (G1) v = v / (1.f + __expf(-v));   // silu
        unsigned int u = f2bf_bits(v);
        unsigned int other = (unsigned int)__shfl_xor((int)u, 1, 64);
        if (!(lane & 1)) {
          const unsigned int w = (u & 0xffffu) | (other << 16);
          const long row = rbase + i * 16 + r;
          const int col = cbase + j * 16;
          *(unsigned int*)(C + row * N + col) = w;
        }
      }
    }
  }
}

// ---------------- combine: out = w0*eo[p0] + w1*eo[p1] + eo[shared] ---------
__global__ __launch_bounds__(256) void combine_kernel(
    const u16* __restrict__ eo, const int* __restrict__ pos2,
    const float* __restrict__ wgt2, const int* __restrict__ offs,
    float* __restrict__ out) {
  const int t = blockIdx.x, tid = threadIdx.x;
  const int p0 = pos2[2 * t], p1 = pos2[2 * t + 1];
  const float w0 = wgt2[2 * t], w1 = wgt2[2 * t + 1];
  const int ps = offs[8] + t;
  const long c = (long)tid * 4;
  const ushort4 a = *(const ushort4*)(eo + (long)p0 * D_ + c);
  const ushort4 b = *(const ushort4*)(eo + (long)p1 * D_ + c);
  const ushort4 s = *(const ushort4*)(eo + (long)ps * D_ + c);
  float4 o;
  o.x = w0 * bf2f(a.x) + w1 * bf2f(b.x) + bf2f(s.x);
  o.y = w0 * bf2f(a.y) + w1 * bf2f(b.y) + bf2f(s.y);
  o.z = w0 * bf2f(a.z) + w1 * bf2f(b.z) + bf2f(s.z);
  o.w = w0 * bf2f(a.w) + w1 * bf2f(b.w) + bf2f(s.w);
  *(float4*)(out + (long)t * D_ + c) = o;
}

// ---------------------------------------------------------------------------
extern "C" void kernel_launch(void* const* d_in, const int* in_sizes, int n_in,
                              void* d_out, int out_size, void* d_ws, size_t ws_size,
                              hipStream_t stream) {
  const float* x   = (const float*)d_in[0];   // [T, D]
  const float* rw  = (const float*)d_in[1];   // [D, E]
  const float* w1  = (const float*)d_in[2];   // [E, D, H]
  const float* w2  = (const float*)d_in[3];   // [E, H, D]
  const float* sw1 = (const float*)d_in[4];   // [D, H]
  const float* sw2 = (const float*)d_in[5];   // [H, D]
  float* out = (float*)d_out;

  char* ws = (char*)d_ws;
  int*   counts      = (int*)(ws + 0);
  int*   cursors     = (int*)(ws + 64);
  int*   offs        = (int*)(ws + 128);
  int*   tile_expert = (int*)(ws + 512);
  int*   tok2        = (int*)(ws + 4096);
  float* wgt2        = (float*)(ws + 4096 + 65536);
  int*   pos2        = (int*)(ws + 4096 + 131072);
  int*   rowtok      = (int*)(ws + 4096 + 196608);

  size_t off = 1u << 20;
  u16* xb  = (u16*)(ws + off); off += (size_t)T_ * D_ * 2;            // 16.8 MB
  u16* w1t = (u16*)(ws + off); off += (size_t)9 * H_ * D_ * 2;        // 75.5 MB
  u16* w2t = (u16*)(ws + off); off += (size_t)9 * D_ * H_ * 2;        // 75.5 MB
  u16* h   = (u16*)(ws + off); off += (size_t)MAXROWS * H_ * 2;       // 209.7 MB
  u16* eo  = (u16*)(ws + off); off += (size_t)MAXROWS * D_ * 2;       // 52.4 MB

  hipMemsetAsync(ws, 0, 256, stream);   // counts + cursors
  router_kernel<<<128, 256, 0, stream>>>(x, rw, counts, tok2, wgt2);
  scan_kernel<<<1, 256, 0, stream>>>(counts, offs, tile_expert, rowtok);
  assign_kernel<<<32, 256, 0, stream>>>(tok2, offs, cursors, rowtok, pos2);
  cvt_x_kernel<<<T_ * D_ / 1024, 256, 0, stream>>>(x, xb);
  transpose_cvt_kernel<<<dim3(H_ / 64, D_ / 64, 9), 256, 0, stream>>>(w1, sw1, w1t, D_, H_);
  transpose_cvt_kernel<<<dim3(D_ / 64, H_ / 64, 9), 256, 0, stream>>>(w2, sw2, w2t, H_, D_);
  // G1: chunk = 24 mt x 32 nt; G2: chunk = 64 mt x 8 nt (R2/R3-proven)
  moe_gemm<true, 24><<<NTILES * (H_ / 128), 256, 0, stream>>>(xb, w1t, h, rowtok, tile_expert);
  moe_gemm<false, 64><<<NTILES * (D_ / 128), 256, 0, stream>>>(h, w2t, eo, rowtok, tile_expert);
  combine_kernel<<<T_, 256, 0, stream>>>(eo, pos2, wgt2, offs, out);
}